// Round 4
// baseline (136.780 us; speedup 1.0000x reference)
//
#include <hip/hip_runtime.h>

// CRF NLL: meet-in-the-middle scan, fwd and bwd chains in SEPARATE WAVES
// (2 waves/block, 128 blocks).
//   fwd (wave 0):  q'[jo] = (sum_i q[i] FM[i][jo]) * e_t[jo], t = 1..255
//   bwd (wave 1):  g'[io] = sum_j BM[io][j] (e_tau[j] g[j]), tau = 511..256
//   meet: forward = C_f + C_b + log(sum_j q[j] * g[j])
//
// R18: SYSTOLIC RING MATVEC VIA DPP. R14-R17 triangulated: pull-style
// cross-lane (readlane ~8cyc, ds_swizzle ~13, LDS round-trip worse) x34
// per step = the 408cyc/step floor. Rotate model: states padded to 48 =
// 3 blocks x 16, mapped to 16-lane DPP rows. Lane (r,p) holds x[16a+p]
// (replicated, a=0..2); accumulator pair U (ring offsets 0-7) / V (8-15)
// rotates via v_mov_dpp row_ror:1 (plain VALU). Matrix stored BY
// DIAGONAL: DU/DV[a][k][lane] = M-coef for (input 16a+p -> output
// 16rc+((p-m)&15)), m=k / 8+k -- register index lane-invariant. Per
// step: 48 fmac + 17 dpp + 3 __shfl (row->all replication) + 3 mul.
// Direction anchor: row_shr:1 = src[n-1] (GPUOpen/rocPRIM scans), so
// ror:1 = src[(n-1)&15]; U needs a final ror:8, V none (virtual pre-rot).
// Pad correctness: exp(-1000)=0 zeroes pad rows/cols; pad x stays 0.
// Kept: renorm folded into prefetched e (off-chain), 4-step lookahead,
// waves_per_eu(1,1), mask-aware bwd renorm, unmasked fwd (len >= 256).

namespace {
constexpr int kB = 128;
constexpr int kS = 512;
constexpr int kT = 36;
constexpr int kStart = 34;
constexpr int kEnd = 35;

__device__ __forceinline__ float readlane_f(float v, int lane) {
    return __builtin_bit_cast(float, __builtin_amdgcn_readlane(__builtin_bit_cast(int, v), lane));
}
__device__ __forceinline__ float ror1_f(float x) {   // dst[p] = src[(p-1)&15] within 16-row
    const int xi = __builtin_bit_cast(int, x);
    return __builtin_bit_cast(float, __builtin_amdgcn_update_dpp(xi, xi, 0x121, 0xF, 0xF, false));
}
__device__ __forceinline__ float ror8_f(float x) {   // dst[p] = src[(p-8)&15]
    const int xi = __builtin_bit_cast(int, x);
    return __builtin_bit_cast(float, __builtin_amdgcn_update_dpp(xi, xi, 0x128, 0xF, 0xF, false));
}

__device__ __forceinline__ float wave_sum(float v) {
#pragma unroll
    for (int off = 32; off; off >>= 1) v += __shfl_xor(v, off, 64);
    return v;
}
__device__ __forceinline__ int wave_sum_i(int v) {
#pragma unroll
    for (int off = 32; off; off >>= 1) v += __shfl_xor(v, off, 64);
    return v;
}

#define FOR8(X) X(0) X(1) X(2) X(3) X(4) X(5) X(6) X(7)

// padded matrix coefficient: exp(trans[row][col]) or 0 outside 36x36
#define XPC(row, col) ((((row) < kT) && ((col) < kT)) ? __expf(trans[(row)*kT + (col)]) : 0.f)
// output index at ring offset m for this lane (rc = coefficient row)
#define JO(m) (16 * rc + ((p - (m)) & 15))

// fwd coefficients: input i = 16a+p (row of trans), output jo (col)
#define FDU(k) const float DU0_##k = XPC(s0, JO(k)), DU1_##k = XPC(s1, JO(k)), DU2_##k = XPC(s2, JO(k));
#define FDV(k) const float DV0_##k = XPC(s0, JO(8 + (k))), DV1_##k = XPC(s1, JO(8 + (k))), DV2_##k = XPC(s2, JO(8 + (k)));
// bwd coefficients: output io (row of trans), input j = 16a+p (col)
#define BDU(k) const float DU0_##k = XPC(JO(k), s0), DU1_##k = XPC(JO(k), s1), DU2_##k = XPC(JO(k), s2);
#define BDV(k) const float DV0_##k = XPC(JO(8 + (k)), s0), DV1_##k = XPC(JO(8 + (k)), s1), DV2_##k = XPC(JO(8 + (k)), s2);

// one ring phase: fmacs at current rotation count, then rotate both accs
#define PHASE(k) \
    U = fmaf(R0, DU0_##k, U); V = fmaf(R0, DV0_##k, V); \
    U = fmaf(R1, DU1_##k, U); V = fmaf(R1, DV1_##k, V); \
    U = fmaf(R2, DU2_##k, U); V = fmaf(R2, DV2_##k, V); \
    U = ror1_f(U); V = ror1_f(V);

// 3-wide load / exp slot helpers (slot s in {0,1,2,3})
#define LD3(t, s) p##s##x = fl0[(t) * kT]; p##s##y = fl1[(t) * kT]; p##s##z = fl2[(t) * kT];
#define EX3(s) e##s##x = __expf(p##s##x); e##s##y = __expf(p##s##y); e##s##z = __expf(p##s##z);

__global__ __attribute__((amdgpu_flat_work_group_size(128, 128),
                          amdgpu_waves_per_eu(1, 1)))
void crf_ring_kernel(const float* __restrict__ feats,   // (B,S,T)
                     const float* __restrict__ trans,   // (T,T)
                     const int* __restrict__ mask,      // (B,S)
                     const int* __restrict__ tags,      // (B,S)
                     float* __restrict__ out) {         // scalar
    const int b = blockIdx.x;
    const int tid = threadIdx.x;
    const int w = tid >> 6;                   // 0 = fwd wave, 1 = bwd wave
    const int j = tid & 63;
    const int p = j & 15;                     // ring position
    const int rr = j >> 4;                    // DPP row
    const int rc = (rr < 2) ? rr : 2;         // coeff row (row3 dups row2, unused)
    const int s0 = p, s1 = 16 + p, s2 = 32 + p;  // states per block (s2 may pad)
    const float* fbase = feats + (size_t)b * kS * kT;
    const float* fl0 = fbase + s0;
    const float* fl1 = fbase + s1;
    const float* fl2 = fbase + ((s2 < kT) ? s2 : (kT - 1));  // clamped col (pad value unused)
    const int* mb = mask + b * kS;
    const int* tb = tags + b * kS;

    __shared__ float gbuf[3][64];   // gamma blocks from bwd wave
    __shared__ float cbbuf;         // C_b from bwd wave

    // ---- sequence length (contiguous-prefix mask); len in [256, 512] ----
    int len = 0;
#pragma unroll
    for (int k = 0; k < kS / 64; ++k) len += mb[k * 64 + j];
    len = __builtin_amdgcn_readfirstlane(wave_sum_i(len));

    float Q0 = 0.f, Q1 = 0.f, Q2 = 0.f, Cf = 0.f;  // fwd state (live into epilogue)

    float p0x, p0y, p0z, p1x, p1y, p1z, p2x, p2y, p2z, p3x, p3y, p3z;
    float e0x, e0y, e0z, e1x, e1y, e1z, e2x, e2y, e2z, e3x, e3y, e3z;

    if (w == 1) {
        // ================== backward wave: tau = 511..256 ==================
        FOR8(BDU) FOR8(BDV)
        float G0 = __expf(trans[s0 * kT + kEnd]);
        float G1 = __expf(trans[s1 * kT + kEnd]);
        float G2 = (s2 < kT) ? __expf(trans[s2 * kT + kEnd]) : 0.f;
        float Cb = 0.f;

        auto bstep = [&](float e0, float e1, float e2, int tau) {
            const float R0 = e0 * G0, R1 = e1 * G1, R2 = e2 * G2;
            float U = 0.f, V = 0.f;
            FOR8(PHASE)
            const float Y = ror8_f(U) + V;     // Y[lane(r,p)] = g'[16r + p]
            const float n0 = __shfl(Y, s0, 64);
            const float n1 = __shfl(Y, s1, 64);
            const float n2 = __shfl(Y, s2, 64);  // s2>=36 reads pad output = 0
            const bool upd = tau < len;
            G0 = upd ? n0 : G0; G1 = upd ? n1 : G1; G2 = upd ? n2 : G2;
        };
        auto renormB = [&](float& e0, float& e1, float& e2, int tau_next) {
            const float mg = readlane_f(G0, 0);      // g[0] > 0
            const float lg = __logf(mg);
            const float rv = __builtin_amdgcn_rcpf(mg);
            if (tau_next < len) { Cb += lg; e0 *= rv; e1 *= rv; e2 *= rv; }
        };

        LD3(511, 0) LD3(510, 1) LD3(509, 2) LD3(508, 3)
        EX3(0) EX3(1) EX3(2) EX3(3)
        LD3(507, 0) LD3(506, 1) LD3(505, 2) LD3(504, 3)

#pragma unroll 1
        for (int g = 0; g < 64; ++g) {
            const int tg = 511 - 4 * g;
            bstep(e0x, e0y, e0z, tg);
            bstep(e1x, e1y, e1z, tg - 1);
            bstep(e2x, e2y, e2z, tg - 2);
            bstep(e3x, e3y, e3z, tg - 3);
            EX3(0) EX3(1) EX3(2) EX3(3)            // e for tau = tg-4..tg-7
            LD3(tg - 8, 0) LD3(tg - 9, 1) LD3(tg - 10, 2) LD3(tg - 11, 3)  // >= 248, valid
            if (g < 63) renormB(e0x, e0y, e0z, tg - 4);  // last fold dropped (exact)
        }
        gbuf[0][j] = G0; gbuf[1][j] = G1; gbuf[2][j] = G2;
        if (j == 0) cbbuf = Cb;
    } else {
        // ================== forward wave: t = 1..255 (never masked) =======
        FOR8(FDU) FOR8(FDV)
        // init from t=0: Cf = a0[0] (uniform), Q = exp(a0 - Cf)
        Cf = fbase[0] + trans[kStart * kT];
        Q0 = __expf(fl0[0] + trans[kStart * kT + s0] - Cf);
        Q1 = __expf(fl1[0] + trans[kStart * kT + s1] - Cf);
        Q2 = (s2 < kT) ? __expf(fl2[0] + trans[kStart * kT + s2] - Cf) : 0.f;

        auto fstep = [&](float e0, float e1, float e2) {
            const float R0 = Q0, R1 = Q1, R2 = Q2;
            float U = 0.f, V = 0.f;
            FOR8(PHASE)
            const float Y = ror8_f(U) + V;     // Y[lane(r,p)] = y[16r + p]
            Q0 = __shfl(Y, s0, 64) * e0;
            Q1 = __shfl(Y, s1, 64) * e1;
            Q2 = __shfl(Y, s2, 64) * e2;       // pad: 0 * e = 0
        };
        auto renormF = [&](float& e0, float& e1, float& e2) {
            const float mf = readlane_f(Q0, 0);      // x[0] > 0
            Cf += __logf(mf);
            const float rv = __builtin_amdgcn_rcpf(mf);
            e0 *= rv; e1 *= rv; e2 *= rv;
        };

        LD3(1, 0) LD3(2, 1) LD3(3, 2) LD3(4, 3)
        EX3(0) EX3(1) EX3(2) EX3(3)
        LD3(5, 0) LD3(6, 1) LD3(7, 2) LD3(8, 3)

#pragma unroll 1
        for (int g = 0; g < 63; ++g) {
            const int t4 = 4 * g + 5;                 // next group's first step
            fstep(e0x, e0y, e0z);
            fstep(e1x, e1y, e1z);
            fstep(e2x, e2y, e2z);
            fstep(e3x, e3y, e3z);
            EX3(0) EX3(1) EX3(2) EX3(3)               // e for t4..t4+3
            LD3(t4 + 4, 0) LD3(t4 + 5, 1) LD3(t4 + 6, 2) LD3(t4 + 7, 3)  // <= 260, valid
            renormF(e0x, e0y, e0z);                   // folds into step t4
        }
        // tail: t = 253, 254, 255 (e-slots hold 253..256)
        fstep(e0x, e0y, e0z);
        fstep(e1x, e1y, e1z);
        fstep(e2x, e2y, e2z);
        // <=3 steps unrenormalized: |q| <= e^~26, safe in f32.
    }

    __syncthreads();

    if (w == 0) {
        // ---- meet: Z = sum_j q[j] g[j]; each (a,p) product replicated over
        //      4 rows (Q via shfl, G via gbuf, both row-invariant) -> /4 exact.
        //      Pad states: Q=0 and G=0 -> contribute 0. ----
        const float Z = wave_sum(Q0 * gbuf[0][j] + Q1 * gbuf[1][j] + Q2 * gbuf[2][j]) * 0.25f;
        const float forward_b = Cf + cbbuf + __logf(Z);

        // ---- gold score (parallel over time steps; j = time lane here) ----
        float gold = 0.f;
        for (int k = j; k < kS; k += 64) {
            if (k < len) {
                const int tg = tb[k];
                const int pv = (k == 0) ? kStart : tb[k - 1];
                gold += fbase[(size_t)k * kT + tg] + trans[pv * kT + tg];
            }
        }
        gold = wave_sum(gold);

        if (j == 0) {
            gold += trans[tb[len - 1] * kT + kEnd];
            atomicAdd(out, (forward_b - gold) * (1.0f / kB));
        }
    }
}

}  // namespace

extern "C" void kernel_launch(void* const* d_in, const int* in_sizes, int n_in,
                              void* d_out, int out_size, void* d_ws, size_t ws_size,
                              hipStream_t stream) {
    const float* feats = (const float*)d_in[0];
    const float* trans = (const float*)d_in[1];
    const int* mask = (const int*)d_in[2];
    const int* tags = (const int*)d_in[3];
    float* out = (float*)d_out;

    (void)hipMemsetAsync(out, 0, sizeof(float), stream);
    crf_ring_kernel<<<dim3(kB), dim3(128), 0, stream>>>(feats, trans, mask, tags, out);
}

// Round 5
// 112.503 us; speedup vs baseline: 1.2158x; 1.2158x over previous
//
#include <hip/hip_runtime.h>

// CRF NLL: meet-in-the-middle VALU scan, fwd and bwd chains in SEPARATE
// WAVES of one block (2 waves/block, 128 blocks).
//   fwd (wave 0):  q'[j] = (sum_i q[i] Fm[i]) * exp(f_t[j]), t = 1..255
//   bwd (wave 1):  p[j] = exp(f_tau[j]) * g[j]; g'[i] = sum_j p[j] Bm[j],
//                  tau = 511..256, holds while tau >= len
//   meet: forward = C_f + C_b + log(sum_j q[j] * g[j])
//
// R19: HYBRID RL+LDS BROADCAST. Five-round synthesis (cyc/step: R14
// interleaved-RL 408, R15 batched 440, R16 swizzle 470, R17 all-LDS 640,
// R18 DPP-ring 814): cross-lane-producer -> VALU-consumer costs ~8-12cyc
// as an ISSUE STALL (R13's 2-chains-1-wave at ~700/pair proves other-work
// doesn't fill it), and R17's LDS round-trip (~150cyc) sat serial on the
// chain with nothing to hide it. Fix = overlap the two latencies:
//   per step: ds_write q -> 6x uniform ds_read_b128 (issued early, data
//   ~150cyc later) ; 12 readlane-fed fmacs run IN THAT SHADOW ; then 24
//   LDS-fed fmacs (pure VGPR, no hazard) + tree + scale.
// Cross-lane stalls/step: 34 -> 12. Terms 34,35 ride in the vec4 reads
// with provably-zero factors (fwd: q[34]=0 col-START, Fm35=0 row-END;
// bwd: Bm34=0 col-START, g[35]=0 row-END) -- exact. Accumulator rotation
// v(n%4) identical to R15 -> bit-identical arithmetic (absmax 0.0).
// Kept from R15 (passed): renorm folded into prefetched emission,
// unmasked 255-step fwd, 8-deep double-buffered prefetch, waves_per_eu(1,1).
// No sched_barrier (R15 lesson).

namespace {
constexpr int kB = 128;
constexpr int kS = 512;
constexpr int kT = 36;
constexpr int kStart = 34;
constexpr int kEnd = 35;

__device__ __forceinline__ float readlane_f(float v, int lane) {
    return __builtin_bit_cast(float, __builtin_amdgcn_readlane(__builtin_bit_cast(int, v), lane));
}

__device__ __forceinline__ float wave_sum(float v) {
#pragma unroll
    for (int off = 32; off; off >>= 1) v += __shfl_xor(v, off, 64);
    return v;
}

__device__ __forceinline__ int wave_sum_i(int v) {
#pragma unroll
    for (int off = 32; off; off >>= 1) v += __shfl_xor(v, off, 64);
    return v;
}

// n = term index, a = accumulator index (n%4, matching R15's FOR34 exactly;
// terms 34,35 append exact +0.0 to accs 2,3)
#define FOR12(X) \
    X(0, 0) X(1, 1) X(2, 2) X(3, 3) X(4, 0) X(5, 1) X(6, 2) X(7, 3) \
    X(8, 0) X(9, 1) X(10, 2) X(11, 3)
#define FOR24(X) \
    X(12, 0) X(13, 1) X(14, 2) X(15, 3) X(16, 0) X(17, 1) X(18, 2) X(19, 3) \
    X(20, 0) X(21, 1) X(22, 2) X(23, 3) X(24, 0) X(25, 1) X(26, 2) X(27, 3) \
    X(28, 0) X(29, 1) X(30, 2) X(31, 3) X(32, 0) X(33, 1) X(34, 2) X(35, 3)
#define FOR36(X) FOR12(X) FOR24(X)

#define FMDECL(n, a) float Fm##n;
#define FMINIT(n, a) Fm##n = __expf(trans[(n)*kT + jc]);
#define BMDECL(n, a) float Bm##n;
#define BMINIT(n, a) Bm##n = __expf(trans[jc * kT + (n)]);
#define RLQ(n, a) const float s##n = readlane_f(srcv, n);
#define FD(n, a) v##a = fmaf(s##n, Fm##n, v##a);
#define BD(n, a) w##a = fmaf(s##n, Bm##n, w##a);

// LDS-fed terms 12..35: issue 6 uniform-address vec4 reads (HW broadcast,
// conflict-free, in-order after the ds_write within this wave)
#define LDSRD(buf) \
    const float4 A0 = *reinterpret_cast<const float4*>((buf) + 12); \
    const float4 A1 = *reinterpret_cast<const float4*>((buf) + 16); \
    const float4 A2 = *reinterpret_cast<const float4*>((buf) + 20); \
    const float4 A3 = *reinterpret_cast<const float4*>((buf) + 24); \
    const float4 A4 = *reinterpret_cast<const float4*>((buf) + 28); \
    const float4 A5 = *reinterpret_cast<const float4*>((buf) + 32);
#define LDSUNPACK \
    const float s12 = A0.x, s13 = A0.y, s14 = A0.z, s15 = A0.w; \
    const float s16 = A1.x, s17 = A1.y, s18 = A1.z, s19 = A1.w; \
    const float s20 = A2.x, s21 = A2.y, s22 = A2.z, s23 = A2.w; \
    const float s24 = A3.x, s25 = A3.y, s26 = A3.z, s27 = A3.w; \
    const float s28 = A4.x, s29 = A4.y, s30 = A4.z, s31 = A4.w; \
    const float s32 = A5.x, s33 = A5.y, s34 = A5.z, s35 = A5.w;

// clamped row loads (values unused when out of range; addr in-bounds)
#define LDF(t) fl[(size_t)(((t) < kS - 1) ? (t) : (kS - 1)) * kT]
#define LDBW(t) fl[(size_t)(((t) > 0) ? (t) : 0) * kT]

__global__ __attribute__((amdgpu_flat_work_group_size(128, 128),
                          amdgpu_waves_per_eu(1, 1)))
void crf_split_kernel(const float* __restrict__ feats,   // (B,S,T)
                      const float* __restrict__ trans,   // (T,T)
                      const int* __restrict__ mask,      // (B,S)
                      const int* __restrict__ tags,      // (B,S)
                      float* __restrict__ out) {         // scalar
    const int b = blockIdx.x;
    const int tid = threadIdx.x;
    const int w = tid >> 6;                   // 0 = fwd wave, 1 = bwd wave
    const int j = tid & 63;                   // lane = state index
    const int jc = (j < kT) ? j : (kT - 1);   // clamped (addressing only)
    const float* fbase = feats + (size_t)b * kS * kT;
    const float* fl = fbase + jc;             // per-lane feats column
    const int* mb = mask + b * kS;
    const int* tb = tags + b * kS;

    __shared__ alignas(16) float xbuf[2][64];  // per-wave broadcast line
    __shared__ float gbuf[64];   // gamma from bwd wave
    __shared__ float cbbuf;      // C_b from bwd wave
    float* xb = &xbuf[w][0];

    // ---- sequence length (contiguous-prefix mask); len in [256, 512] ----
    int len = 0;
#pragma unroll
    for (int k = 0; k < kS / 64; ++k) len += mb[k * 64 + j];
    len = __builtin_amdgcn_readfirstlane(wave_sum_i(len));  // SGPR

    float q = 0.f, Cf = 0.f;  // fwd results (live into the epilogue)

    if (w == 1) {
        // ================== backward wave: tau = 511..256 ==================
        FOR36(BMDECL)
        FOR36(BMINIT)
        float g = (j < kT) ? __expf(trans[j * kT + kEnd]) : 0.f;
        float Cb = 0.f;

        auto bstep = [&](float eb, int tau) {
            const float srcv = eb * g;
            xb[j] = srcv;                       // ds_write_b32: start RT now
            LDSRD(xb)                           // 6x uniform ds_read_b128
            float w0 = 0.f, w1 = 0.f, w2 = 0.f, w3 = 0.f;
            FOR12(RLQ)                          // 12 readlanes in LDS shadow
            FOR12(BD)
            LDSUNPACK
            FOR24(BD)                           // LDS-fed, pure VGPR
            const float ng = (w0 + w1) + (w2 + w3);
            g = (tau < len) ? ng : g;           // hold while masked
        };
        // mask-aware fold: uniform scale applied to the NEXT step's
        // prefetched emission (off the serial chain). Only applied+logged
        // when that step actually updates g (holds keep g constant & O(1)).
        auto renormB = [&](float& eb_next, int tau_next) {
            const float mg = readlane_f(g, 0);
            const float lg = __logf(mg);
            const float r = __builtin_amdgcn_rcpf(mg);
            if (tau_next < len) { Cb += lg; eb_next *= r; }
        };

        float pA0, pA1, pA2, pA3, pA4, pA5, pA6, pA7;
        float pB0, pB1, pB2, pB3, pB4, pB5, pB6, pB7;
        float eA0, eA1, eA2, eA3, eA4, eA5, eA6, eA7;
        pA0 = LDBW(511); pA1 = LDBW(510); pA2 = LDBW(509); pA3 = LDBW(508);
        pA4 = LDBW(507); pA5 = LDBW(506); pA6 = LDBW(505); pA7 = LDBW(504);
        eA0 = __expf(pA0); eA1 = __expf(pA1); eA2 = __expf(pA2); eA3 = __expf(pA3);
        eA4 = __expf(pA4); eA5 = __expf(pA5); eA6 = __expf(pA6); eA7 = __expf(pA7);

        int it0 = 0;
        while (it0 < kS / 2) {
            pB0 = LDBW(503 - it0); pB1 = LDBW(502 - it0); pB2 = LDBW(501 - it0); pB3 = LDBW(500 - it0);
            pB4 = LDBW(499 - it0); pB5 = LDBW(498 - it0); pB6 = LDBW(497 - it0); pB7 = LDBW(496 - it0);
            bstep(eA0, 511 - it0); bstep(eA1, 510 - it0);
            bstep(eA2, 509 - it0); bstep(eA3, 508 - it0);
            renormB(eA4, 507 - it0);
            bstep(eA4, 507 - it0); bstep(eA5, 506 - it0);
            bstep(eA6, 505 - it0); bstep(eA7, 504 - it0);
            eA0 = __expf(pB0); eA1 = __expf(pB1); eA2 = __expf(pB2); eA3 = __expf(pB3);
            eA4 = __expf(pB4); eA5 = __expf(pB5); eA6 = __expf(pB6); eA7 = __expf(pB7);
            renormB(eA0, 503 - it0);

            pA0 = LDBW(495 - it0); pA1 = LDBW(494 - it0); pA2 = LDBW(493 - it0); pA3 = LDBW(492 - it0);
            pA4 = LDBW(491 - it0); pA5 = LDBW(490 - it0); pA6 = LDBW(489 - it0); pA7 = LDBW(488 - it0);
            bstep(eA0, 503 - it0); bstep(eA1, 502 - it0);
            bstep(eA2, 501 - it0); bstep(eA3, 500 - it0);
            renormB(eA4, 499 - it0);
            bstep(eA4, 499 - it0); bstep(eA5, 498 - it0);
            bstep(eA6, 497 - it0); bstep(eA7, 496 - it0);
            eA0 = __expf(pA0); eA1 = __expf(pA1); eA2 = __expf(pA2); eA3 = __expf(pA3);
            eA4 = __expf(pA4); eA5 = __expf(pA5); eA6 = __expf(pA6); eA7 = __expf(pA7);
            // cross-iteration fold target only exists for non-final iters;
            // dropping the last renorm is exact (result invariant to it).
            if (it0 < kS / 2 - 16) renormB(eA0, 495 - it0);
            it0 += 16;
        }
        gbuf[j] = g;              // gamma_256 (lanes >= 36 and END: exactly 0)
        if (j == 0) cbbuf = Cb;
    } else {
        // ================== forward wave: t = 1..255 (never masked) =======
        FOR36(FMDECL)
        FOR36(FMINIT)
        const float a0 = (j < kT) ? (fl[0] + trans[kStart * kT + jc]) : -1e30f;
        Cf = readlane_f(a0, 0);
        q = __expf(a0 - Cf);

        auto fstep = [&](float ef) {
            const float srcv = q;
            xb[j] = srcv;                       // ds_write_b32: start RT now
            LDSRD(xb)                           // 6x uniform ds_read_b128
            float v0 = 0.f, v1 = 0.f, v2 = 0.f, v3 = 0.f;
            FOR12(RLQ)                          // 12 readlanes in LDS shadow
            FOR12(FD)
            LDSUNPACK
            FOR24(FD)                           // LDS-fed, pure VGPR
            q = ((v0 + v1) + (v2 + v3)) * ef;
        };
        auto renormF = [&](float& ef_next) {  // fold scale into prefetched emission
            const float mf = readlane_f(q, 0);
            Cf += __logf(mf);
            ef_next *= __builtin_amdgcn_rcpf(mf);
        };

        float pA0, pA1, pA2, pA3, pA4, pA5, pA6, pA7;
        float pB0, pB1, pB2, pB3, pB4, pB5, pB6, pB7;
        float eA0, eA1, eA2, eA3, eA4, eA5, eA6, eA7;
        pA0 = LDF(1); pA1 = LDF(2); pA2 = LDF(3); pA3 = LDF(4);
        pA4 = LDF(5); pA5 = LDF(6); pA6 = LDF(7); pA7 = LDF(8);
        eA0 = __expf(pA0); eA1 = __expf(pA1); eA2 = __expf(pA2); eA3 = __expf(pA3);
        eA4 = __expf(pA4); eA5 = __expf(pA5); eA6 = __expf(pA6); eA7 = __expf(pA7);

        int it0 = 0;
        while (it0 < 240) {  // 15 iters -> t = 1..240
            pB0 = LDF(it0 + 9);  pB1 = LDF(it0 + 10); pB2 = LDF(it0 + 11); pB3 = LDF(it0 + 12);
            pB4 = LDF(it0 + 13); pB5 = LDF(it0 + 14); pB6 = LDF(it0 + 15); pB7 = LDF(it0 + 16);
            fstep(eA0); fstep(eA1); fstep(eA2); fstep(eA3);
            renormF(eA4);
            fstep(eA4); fstep(eA5); fstep(eA6); fstep(eA7);
            eA0 = __expf(pB0); eA1 = __expf(pB1); eA2 = __expf(pB2); eA3 = __expf(pB3);
            eA4 = __expf(pB4); eA5 = __expf(pB5); eA6 = __expf(pB6); eA7 = __expf(pB7);
            renormF(eA0);

            pA0 = LDF(it0 + 17); pA1 = LDF(it0 + 18); pA2 = LDF(it0 + 19); pA3 = LDF(it0 + 20);
            pA4 = LDF(it0 + 21); pA5 = LDF(it0 + 22); pA6 = LDF(it0 + 23); pA7 = LDF(it0 + 24);
            fstep(eA0); fstep(eA1); fstep(eA2); fstep(eA3);
            renormF(eA4);
            fstep(eA4); fstep(eA5); fstep(eA6); fstep(eA7);
            eA0 = __expf(pA0); eA1 = __expf(pA1); eA2 = __expf(pA2); eA3 = __expf(pA3);
            eA4 = __expf(pA4); eA5 = __expf(pA5); eA6 = __expf(pA6); eA7 = __expf(pA7);
            renormF(eA0);  // folds into next iter's (or the tail's) first step
            it0 += 16;
        }
        // tail: t = 241..255 (eA holds e[241..248], fold already in eA0)
        float pT0 = LDF(249), pT1 = LDF(250), pT2 = LDF(251), pT3 = LDF(252);
        float pT4 = LDF(253), pT5 = LDF(254), pT6 = LDF(255);
        fstep(eA0); fstep(eA1); fstep(eA2); fstep(eA3);
        renormF(eA4);
        fstep(eA4); fstep(eA5); fstep(eA6); fstep(eA7);
        float eT0 = __expf(pT0), eT1 = __expf(pT1), eT2 = __expf(pT2), eT3 = __expf(pT3);
        float eT4 = __expf(pT4), eT5 = __expf(pT5), eT6 = __expf(pT6);
        renormF(eT0);
        fstep(eT0); fstep(eT1); fstep(eT2); fstep(eT3);
        renormF(eT4);
        fstep(eT4); fstep(eT5); fstep(eT6);
        // q left unrenormalized for <=3 steps: |q| <= e^~26, safe in f32.
    }

    __syncthreads();

    if (w == 0) {
        // ---- meet: Z = sum_j q[j] * gamma[j]; gamma is exactly 0 for
        //      START-unreachable / junk lanes, so the sum is exact ----
        const float Z = wave_sum(q * gbuf[j]);
        const float forward_b = Cf + cbbuf + __logf(Z);

        // ---- gold score (parallel over time steps) ----
        float gold = 0.f;
        for (int k = j; k < kS; k += 64) {
            if (k < len) {
                const int tg = tb[k];
                const int pv = (k == 0) ? kStart : tb[k - 1];
                gold += fbase[(size_t)k * kT + tg] + trans[pv * kT + tg];
            }
        }
        gold = wave_sum(gold);

        if (j == 0) {
            gold += trans[tb[len - 1] * kT + kEnd];
            atomicAdd(out, (forward_b - gold) * (1.0f / kB));
        }
    }
}

}  // namespace

extern "C" void kernel_launch(void* const* d_in, const int* in_sizes, int n_in,
                              void* d_out, int out_size, void* d_ws, size_t ws_size,
                              hipStream_t stream) {
    const float* feats = (const float*)d_in[0];
    const float* trans = (const float*)d_in[1];
    const int* mask = (const int*)d_in[2];
    const int* tags = (const int*)d_in[3];
    float* out = (float*)d_out;

    (void)hipMemsetAsync(out, 0, sizeof(float), stream);
    crf_split_kernel<<<dim3(kB), dim3(128), 0, stream>>>(feats, trans, mask, tags, out);
}

// Round 7
// 98.945 us; speedup vs baseline: 1.3824x; 1.1370x over previous
//
#include <hip/hip_runtime.h>

// CRF NLL: 5-way SEGMENTED chains with rank-1 bridges, 8 waves/block,
// 128 blocks. Seven per-step structures (R14..R20) all landed >=400
// cyc/step for the 34-state broadcast -- the per-step cost is structural.
// So cut CHAIN LENGTH instead: products of strictly-positive matrices
// collapse to rank-1 at (lam2/lam1)^len (here ~0.02/step -- segments
// >=47 steps are rank-1 to << f32 eps). For rank-1 P: P x = y (z.x)/(v.y)
// EXACTLY, with y = P u (fwd probe), z = P^T v (bwd probe).
// Partition t = 1..len-1 into 5 chunks of c = ceil((len-1)/5) <= 103:
//   w0: real fwd  alpha, t in [1, c]          (init from t=0 + START)
//   w1-3: fwd probes y_i over chunk i         (u = ones, u[START] = 0)
//   w4-6: bwd probes z_i over chunk i         (v = ones, v[END] = 0)
//   w7: real bwd gamma, tau = len-1 .. 4c+1   (init exp(trans[:,END]);
//       mask holds (tau >= len) are exact no-ops -> skipped entirely)
// Meet: log Z = C_a + C_z1 + C_z2 + C_z3 + C_g + log(z1.a) + log(z2.y1)
//             + log(z3.y2) + log(g.y3) - log(sum y1) - log(sum y2)
//             - log(sum y3)    (C_y's cancel exactly).
// Probe inits zero the START/END components so the 34-term dot stays
// exact (Fm[END-row]=0, Bm[START-col]=0, q[START]=0, g[END]=0).
// Per-step machinery = R14's best (interleaved readlane+fmac, 408cyc);
// pad steps (chain lengths differ by <=4) predicated via s<cnt select;
// renorm folded into next group's first emission, guarded to fold only
// into ACTIVE steps. 2 waves/SIMD: 2nd wave's ~165 busy cyc fill the
// 1st's ~245 stall cyc.

namespace {
constexpr int kB = 128;
constexpr int kS = 512;
constexpr int kT = 36;
constexpr int kStart = 34;
constexpr int kEnd = 35;

__device__ __forceinline__ float readlane_f(float v, int lane) {
    return __builtin_bit_cast(float, __builtin_amdgcn_readlane(__builtin_bit_cast(int, v), lane));
}

__device__ __forceinline__ float wave_sum(float v) {
#pragma unroll
    for (int off = 32; off; off >>= 1) v += __shfl_xor(v, off, 64);
    return v;
}
__device__ __forceinline__ int wave_sum_i(int v) {
#pragma unroll
    for (int off = 32; off; off >>= 1) v += __shfl_xor(v, off, 64);
    return v;
}

// n = term index, a = accumulator index (rotates 0..3 to break fma chains)
#define FOR34(X) \
    X(0, 0) X(1, 1) X(2, 2) X(3, 3) X(4, 0) X(5, 1) X(6, 2) X(7, 3) \
    X(8, 0) X(9, 1) X(10, 2) X(11, 3) X(12, 0) X(13, 1) X(14, 2) X(15, 3) \
    X(16, 0) X(17, 1) X(18, 2) X(19, 3) X(20, 0) X(21, 1) X(22, 2) X(23, 3) \
    X(24, 0) X(25, 1) X(26, 2) X(27, 3) X(28, 0) X(29, 1) X(30, 2) X(31, 3) \
    X(32, 0) X(33, 1)

#define FMDECL(n, a) float Fm##n;
#define FMINIT(n, a) Fm##n = __expf(trans[(n)*kT + jc]);
#define BMDECL(n, a) float Bm##n;
#define BMINIT(n, a) Bm##n = __expf(trans[jc * kT + (n)]);
#define FDOT(n, a) v##a = fmaf(readlane_f(q, n), Fm##n, v##a);
#define BDOT(n, a) w##a = fmaf(readlane_f(pp, n), Bm##n, w##a);

// clamped feats row load (clamp to [0, kS-1]; clamped values are only
// consumed by predicated-off pad steps)
#define LDT(t) fl[(size_t)(((t) < 0) ? 0 : (((t) > kS - 1) ? (kS - 1) : (t))) * kT]

__global__ __attribute__((amdgpu_flat_work_group_size(512, 512)))
void crf_seg_kernel(const float* __restrict__ feats,   // (B,S,T)
                    const float* __restrict__ trans,   // (T,T)
                    const int* __restrict__ mask,      // (B,S)
                    const int* __restrict__ tags,      // (B,S)
                    float* __restrict__ out) {         // scalar
    const int b = blockIdx.x;
    const int tid = threadIdx.x;
    const int wv = tid >> 6;                  // wave role 0..7
    const int j = tid & 63;                   // lane = state index
    const int jc = (j < kT) ? j : (kT - 1);   // clamped (addressing only)
    const float* fbase = feats + (size_t)b * kS * kT;
    const float* fl = fbase + jc;             // per-lane feats column
    const int* mb = mask + b * kS;
    const int* tb = tags + b * kS;

    __shared__ float vec[8][64];  // final vectors: 0=a,1..3=y,4..6=z,7=g
    __shared__ float cc[8];       // per-chain log constants

    // ---- sequence length (contiguous-prefix mask); len in [256, 512] ----
    int len = 0;
#pragma unroll
    for (int k = 0; k < kS / 64; ++k) len += mb[k * 64 + j];
    len = __builtin_amdgcn_readfirstlane(wave_sum_i(len));

    const int c = (len + 3) / 5;     // ceil((len-1)/5), in [51, 103]
    const int Gp = (c + 3) >> 2;     // 4-step groups covering c steps

    float C = 0.f;

    if (wv < 4) {
        // ============ forward-direction chains (w0 real, w1-3 probes) ====
        FOR34(FMDECL)
        FOR34(FMINIT)
        const int t0 = 1 + wv * c;   // chunk start (wv=0 -> t=1)
        const int cnt = c;
        float q;
        if (wv == 0) {
            const float a0 = (j < kT) ? (fl[0] + trans[kStart * kT + jc]) : -1e30f;
            C = readlane_f(a0, 0);
            q = __expf(a0 - C);
        } else {
            q = (jc == kStart) ? 0.f : 1.f;   // u, with u[START]=0
        }

        auto fstep = [&](float ef, int s) {
            float v0 = 0.f, v1 = 0.f, v2 = 0.f, v3 = 0.f;
            FOR34(FDOT)
            const float nq = ((v0 + v1) + (v2 + v3)) * ef;
            q = (s < cnt) ? nq : q;           // pad steps hold
        };

        float p0, p1, p2, p3, e0, e1, e2, e3;
        p0 = LDT(t0 + 0); p1 = LDT(t0 + 1); p2 = LDT(t0 + 2); p3 = LDT(t0 + 3);
        e0 = __expf(p0); e1 = __expf(p1); e2 = __expf(p2); e3 = __expf(p3);
        p0 = LDT(t0 + 4); p1 = LDT(t0 + 5); p2 = LDT(t0 + 6); p3 = LDT(t0 + 7);

#pragma unroll 1
        for (int g = 0; g < Gp; ++g) {
            const int s = 4 * g;
            fstep(e0, s); fstep(e1, s + 1); fstep(e2, s + 2); fstep(e3, s + 3);
            e0 = __expf(p0); e1 = __expf(p1); e2 = __expf(p2); e3 = __expf(p3);
            p0 = LDT(t0 + s + 8);  p1 = LDT(t0 + s + 9);
            p2 = LDT(t0 + s + 10); p3 = LDT(t0 + s + 11);
            if (s + 4 < cnt) {  // fold renorm only into an ACTIVE next step
                const float mf = readlane_f(q, 0);
                C += __logf(mf);
                e0 *= __builtin_amdgcn_rcpf(mf);
            }
        }
        vec[wv][j] = q;
        if (j == 0) cc[wv] = C;
    } else {
        // ============ backward-direction chains (w4-6 probes, w7 real) ===
        FOR34(BMDECL)
        FOR34(BMINIT)
        const bool real = (wv == 7);
        const int tau0 = real ? (len - 1) : ((wv - 2) * c);  // w4:2c w5:3c w6:4c
        const int cnt = real ? (len - 1 - 4 * c) : c;        // in [c-4, c]
        float gg = real ? __expf(trans[jc * kT + kEnd])      // g[END]=0 exactly
                        : ((jc == kEnd) ? 0.f : 1.f);        // v, v[END]=0

        auto bstep = [&](float eb, int s) {
            const float pp = eb * gg;
            float w0 = 0.f, w1 = 0.f, w2 = 0.f, w3 = 0.f;
            FOR34(BDOT)
            const float ng = (w0 + w1) + (w2 + w3);
            gg = (s < cnt) ? ng : gg;         // pad steps hold
        };

        float p0, p1, p2, p3, e0, e1, e2, e3;
        p0 = LDT(tau0 - 0); p1 = LDT(tau0 - 1); p2 = LDT(tau0 - 2); p3 = LDT(tau0 - 3);
        e0 = __expf(p0); e1 = __expf(p1); e2 = __expf(p2); e3 = __expf(p3);
        p0 = LDT(tau0 - 4); p1 = LDT(tau0 - 5); p2 = LDT(tau0 - 6); p3 = LDT(tau0 - 7);

#pragma unroll 1
        for (int g = 0; g < Gp; ++g) {
            const int s = 4 * g;
            bstep(e0, s); bstep(e1, s + 1); bstep(e2, s + 2); bstep(e3, s + 3);
            e0 = __expf(p0); e1 = __expf(p1); e2 = __expf(p2); e3 = __expf(p3);
            p0 = LDT(tau0 - s - 8);  p1 = LDT(tau0 - s - 9);
            p2 = LDT(tau0 - s - 10); p3 = LDT(tau0 - s - 11);
            if (s + 4 < cnt) {
                const float mg = readlane_f(gg, 0);
                C += __logf(mg);
                e0 *= __builtin_amdgcn_rcpf(mg);
            }
        }
        vec[wv][j] = gg;
        if (j == 0) cc[wv] = C;
    }

    __syncthreads();

    if (wv == 0) {
        // ---- meet via rank-1 bridges (lanes >= 36 masked out) ----
        const float msk = (j < kT) ? 1.f : 0.f;
        const float d1 = wave_sum(msk * vec[4][j] * vec[0][j]);  // z1 . alpha
        const float d2 = wave_sum(msk * vec[5][j] * vec[1][j]);  // z2 . y1
        const float d3 = wave_sum(msk * vec[6][j] * vec[2][j]);  // z3 . y2
        const float d4 = wave_sum(msk * vec[7][j] * vec[3][j]);  // gamma . y3
        const float n1 = wave_sum(msk * vec[1][j]);              // v . y1 (v=1)
        const float n2 = wave_sum(msk * vec[2][j]);
        const float n3 = wave_sum(msk * vec[3][j]);
        const float forward_b = cc[0] + cc[4] + cc[5] + cc[6] + cc[7]
            + __logf(d1) + __logf(d2) + __logf(d3) + __logf(d4)
            - __logf(n1) - __logf(n2) - __logf(n3);

        // ---- gold score (parallel over time steps) ----
        float gold = 0.f;
        for (int k = j; k < kS; k += 64) {
            if (k < len) {
                const int tg = tb[k];
                const int pv = (k == 0) ? kStart : tb[k - 1];
                gold += fbase[(size_t)k * kT + tg] + trans[pv * kT + tg];
            }
        }
        gold = wave_sum(gold);

        if (j == 0) {
            gold += trans[tb[len - 1] * kT + kEnd];
            atomicAdd(out, (forward_b - gold) * (1.0f / kB));
        }
    }
}

}  // namespace

extern "C" void kernel_launch(void* const* d_in, const int* in_sizes, int n_in,
                              void* d_out, int out_size, void* d_ws, size_t ws_size,
                              hipStream_t stream) {
    const float* feats = (const float*)d_in[0];
    const float* trans = (const float*)d_in[1];
    const int* mask = (const int*)d_in[2];
    const int* tags = (const int*)d_in[3];
    float* out = (float*)d_out;

    (void)hipMemsetAsync(out, 0, sizeof(float), stream);
    crf_seg_kernel<<<dim3(kB), dim3(512), 0, stream>>>(feats, trans, mask, tags, out);
}

// Round 8
// 93.878 us; speedup vs baseline: 1.4570x; 1.0540x over previous
//
#include <hip/hip_runtime.h>

// CRF NLL: 5-way SEGMENTED chains with rank-1 bridges -- ONE CHAIN PER
// SIMD. R21 proved the bridge math exact (absmax 0.0) but placed 8
// chains on 4 SIMDs (2 waves/SIMD): per-step-slot ~970 cyc showed the
// two co-resident chains SERIALIZE (readlane-dominated steps stall the
// SIMD issue port; R13's 2-chains-1-wave ~700cyc/pair agrees -- the
// ~9cyc/cross-lane-op cost is issue occupancy, not hideable latency).
// R22: 1024 blocks x 64 threads; block = (batch b = bid>>3, role = bid&7);
// waves_per_eu(1,1) caps 1 wave/SIMD -> 4 blocks/CU x 256 CU = 1024
// SIMDs, zero sharing. Chains write (vec, C) to __device__ globals; a
// second tiny kernel does the bridge-meet + gold (same-stream kernel
// boundary = release/acquire fence). Chain step code = R21 verbatim:
//   chunks c = ceil((len-1)/5) <= 103:
//   role 0: real fwd alpha  t in [1, c]
//   roles 1-3: fwd probes y_i (u = 1, u[START] = 0), chunks 2-4
//   roles 4-6: bwd probes z_i (v = 1, v[END] = 0),  chunks 2-4
//   role 7: real bwd gamma tau = len-1 .. 4c+1 (mask holds = exact no-ops)
// Meet: log Z = C_a + C_z1 + C_z2 + C_z3 + C_g + log(z1.a) + log(z2.y1)
//             + log(z3.y2) + log(g.y3) - log(sum y1) - log(sum y2)
//             - log(sum y3)   (rank-1 segment products: exact at len>=47).

namespace {
constexpr int kB = 128;
constexpr int kS = 512;
constexpr int kT = 36;
constexpr int kStart = 34;
constexpr int kEnd = 35;

__device__ float g_vec[kB * 8][64];  // final chain vectors
__device__ float g_cc[kB * 8];       // per-chain log constants

__device__ __forceinline__ float readlane_f(float v, int lane) {
    return __builtin_bit_cast(float, __builtin_amdgcn_readlane(__builtin_bit_cast(int, v), lane));
}

__device__ __forceinline__ float wave_sum(float v) {
#pragma unroll
    for (int off = 32; off; off >>= 1) v += __shfl_xor(v, off, 64);
    return v;
}
__device__ __forceinline__ int wave_sum_i(int v) {
#pragma unroll
    for (int off = 32; off; off >>= 1) v += __shfl_xor(v, off, 64);
    return v;
}

// n = term index, a = accumulator index (rotates 0..3 to break fma chains)
#define FOR34(X) \
    X(0, 0) X(1, 1) X(2, 2) X(3, 3) X(4, 0) X(5, 1) X(6, 2) X(7, 3) \
    X(8, 0) X(9, 1) X(10, 2) X(11, 3) X(12, 0) X(13, 1) X(14, 2) X(15, 3) \
    X(16, 0) X(17, 1) X(18, 2) X(19, 3) X(20, 0) X(21, 1) X(22, 2) X(23, 3) \
    X(24, 0) X(25, 1) X(26, 2) X(27, 3) X(28, 0) X(29, 1) X(30, 2) X(31, 3) \
    X(32, 0) X(33, 1)

#define FMDECL(n, a) float Fm##n;
#define FMINIT(n, a) Fm##n = __expf(trans[(n)*kT + jc]);
#define BMDECL(n, a) float Bm##n;
#define BMINIT(n, a) Bm##n = __expf(trans[jc * kT + (n)]);
#define FDOT(n, a) v##a = fmaf(readlane_f(q, n), Fm##n, v##a);
#define BDOT(n, a) w##a = fmaf(readlane_f(pp, n), Bm##n, w##a);

// clamped feats row load (clamp to [0, kS-1]; clamped values are only
// consumed by predicated-off pad steps)
#define LDT(t) fl[(size_t)(((t) < 0) ? 0 : (((t) > kS - 1) ? (kS - 1) : (t))) * kT]

__device__ __forceinline__ int seq_len(const int* mb, int j) {
    int len = 0;
#pragma unroll
    for (int k = 0; k < kS / 64; ++k) len += mb[k * 64 + j];
    return __builtin_amdgcn_readfirstlane(wave_sum_i(len));
}

__global__ __attribute__((amdgpu_flat_work_group_size(64, 64),
                          amdgpu_waves_per_eu(1, 1)))
void crf_chain_kernel(const float* __restrict__ feats,   // (B,S,T)
                      const float* __restrict__ trans,   // (T,T)
                      const int* __restrict__ mask) {    // (B,S)
    const int b = blockIdx.x >> 3;
    const int wv = blockIdx.x & 7;            // chain role 0..7
    const int j = threadIdx.x;                // lane = state index
    const int jc = (j < kT) ? j : (kT - 1);   // clamped (addressing only)
    const float* fbase = feats + (size_t)b * kS * kT;
    const float* fl = fbase + jc;             // per-lane feats column
    const int* mb = mask + b * kS;

    const int len = seq_len(mb, j);           // in [256, 512]
    const int c = (len + 3) / 5;              // ceil((len-1)/5), in [51, 103]
    const int Gp = (c + 3) >> 2;              // 4-step groups covering c steps

    float C = 0.f;

    if (wv < 4) {
        // ============ forward-direction chains (0 real, 1-3 probes) ======
        FOR34(FMDECL)
        FOR34(FMINIT)
        const int t0 = 1 + wv * c;   // chunk start (wv=0 -> t=1)
        const int cnt = c;
        float q;
        if (wv == 0) {
            const float a0 = (j < kT) ? (fl[0] + trans[kStart * kT + jc]) : -1e30f;
            C = readlane_f(a0, 0);
            q = __expf(a0 - C);
        } else {
            q = (jc == kStart) ? 0.f : 1.f;   // u, with u[START]=0
        }

        auto fstep = [&](float ef, int s) {
            float v0 = 0.f, v1 = 0.f, v2 = 0.f, v3 = 0.f;
            FOR34(FDOT)
            const float nq = ((v0 + v1) + (v2 + v3)) * ef;
            q = (s < cnt) ? nq : q;           // pad steps hold
        };

        float p0, p1, p2, p3, e0, e1, e2, e3;
        p0 = LDT(t0 + 0); p1 = LDT(t0 + 1); p2 = LDT(t0 + 2); p3 = LDT(t0 + 3);
        e0 = __expf(p0); e1 = __expf(p1); e2 = __expf(p2); e3 = __expf(p3);
        p0 = LDT(t0 + 4); p1 = LDT(t0 + 5); p2 = LDT(t0 + 6); p3 = LDT(t0 + 7);

#pragma unroll 1
        for (int g = 0; g < Gp; ++g) {
            const int s = 4 * g;
            fstep(e0, s); fstep(e1, s + 1); fstep(e2, s + 2); fstep(e3, s + 3);
            e0 = __expf(p0); e1 = __expf(p1); e2 = __expf(p2); e3 = __expf(p3);
            p0 = LDT(t0 + s + 8);  p1 = LDT(t0 + s + 9);
            p2 = LDT(t0 + s + 10); p3 = LDT(t0 + s + 11);
            if (s + 4 < cnt) {  // fold renorm only into an ACTIVE next step
                const float mf = readlane_f(q, 0);
                C += __logf(mf);
                e0 *= __builtin_amdgcn_rcpf(mf);
            }
        }
        g_vec[blockIdx.x][j] = q;
        if (j == 0) g_cc[blockIdx.x] = C;
    } else {
        // ============ backward-direction chains (4-6 probes, 7 real) =====
        FOR34(BMDECL)
        FOR34(BMINIT)
        const bool real = (wv == 7);
        const int tau0 = real ? (len - 1) : ((wv - 2) * c);  // 4:2c 5:3c 6:4c
        const int cnt = real ? (len - 1 - 4 * c) : c;        // in [c-4, c]
        float gg = real ? __expf(trans[jc * kT + kEnd])      // g[END]=0 exactly
                        : ((jc == kEnd) ? 0.f : 1.f);        // v, v[END]=0

        auto bstep = [&](float eb, int s) {
            const float pp = eb * gg;
            float w0 = 0.f, w1 = 0.f, w2 = 0.f, w3 = 0.f;
            FOR34(BDOT)
            const float ng = (w0 + w1) + (w2 + w3);
            gg = (s < cnt) ? ng : gg;         // pad steps hold
        };

        float p0, p1, p2, p3, e0, e1, e2, e3;
        p0 = LDT(tau0 - 0); p1 = LDT(tau0 - 1); p2 = LDT(tau0 - 2); p3 = LDT(tau0 - 3);
        e0 = __expf(p0); e1 = __expf(p1); e2 = __expf(p2); e3 = __expf(p3);
        p0 = LDT(tau0 - 4); p1 = LDT(tau0 - 5); p2 = LDT(tau0 - 6); p3 = LDT(tau0 - 7);

#pragma unroll 1
        for (int g = 0; g < Gp; ++g) {
            const int s = 4 * g;
            bstep(e0, s); bstep(e1, s + 1); bstep(e2, s + 2); bstep(e3, s + 3);
            e0 = __expf(p0); e1 = __expf(p1); e2 = __expf(p2); e3 = __expf(p3);
            p0 = LDT(tau0 - s - 8);  p1 = LDT(tau0 - s - 9);
            p2 = LDT(tau0 - s - 10); p3 = LDT(tau0 - s - 11);
            if (s + 4 < cnt) {
                const float mg = readlane_f(gg, 0);
                C += __logf(mg);
                e0 *= __builtin_amdgcn_rcpf(mg);
            }
        }
        g_vec[blockIdx.x][j] = gg;
        if (j == 0) g_cc[blockIdx.x] = C;
    }
}

__global__ __attribute__((amdgpu_flat_work_group_size(64, 64)))
void crf_meet_kernel(const float* __restrict__ feats,   // (B,S,T)
                     const float* __restrict__ trans,   // (T,T)
                     const int* __restrict__ mask,      // (B,S)
                     const int* __restrict__ tags,      // (B,S)
                     float* __restrict__ out) {         // scalar
    const int b = blockIdx.x;
    const int j = threadIdx.x;
    const float* fbase = feats + (size_t)b * kS * kT;
    const int* mb = mask + b * kS;
    const int* tb = tags + b * kS;
    const int len = seq_len(mb, j);
    const int base = b * 8;

    // ---- meet via rank-1 bridges (lanes >= 36 masked out) ----
    const float msk = (j < kT) ? 1.f : 0.f;
    const float d1 = wave_sum(msk * g_vec[base + 4][j] * g_vec[base + 0][j]);  // z1 . alpha
    const float d2 = wave_sum(msk * g_vec[base + 5][j] * g_vec[base + 1][j]);  // z2 . y1
    const float d3 = wave_sum(msk * g_vec[base + 6][j] * g_vec[base + 2][j]);  // z3 . y2
    const float d4 = wave_sum(msk * g_vec[base + 7][j] * g_vec[base + 3][j]);  // gamma . y3
    const float n1 = wave_sum(msk * g_vec[base + 1][j]);                       // v . y1
    const float n2 = wave_sum(msk * g_vec[base + 2][j]);
    const float n3 = wave_sum(msk * g_vec[base + 3][j]);
    const float forward_b = g_cc[base + 0] + g_cc[base + 4] + g_cc[base + 5]
        + g_cc[base + 6] + g_cc[base + 7]
        + __logf(d1) + __logf(d2) + __logf(d3) + __logf(d4)
        - __logf(n1) - __logf(n2) - __logf(n3);

    // ---- gold score (parallel over time steps) ----
    float gold = 0.f;
    for (int k = j; k < kS; k += 64) {
        if (k < len) {
            const int tg = tb[k];
            const int pv = (k == 0) ? kStart : tb[k - 1];
            gold += fbase[(size_t)k * kT + tg] + trans[pv * kT + tg];
        }
    }
    gold = wave_sum(gold);

    if (j == 0) {
        gold += trans[tb[len - 1] * kT + kEnd];
        atomicAdd(out, (forward_b - gold) * (1.0f / kB));
    }
}

}  // namespace

extern "C" void kernel_launch(void* const* d_in, const int* in_sizes, int n_in,
                              void* d_out, int out_size, void* d_ws, size_t ws_size,
                              hipStream_t stream) {
    const float* feats = (const float*)d_in[0];
    const float* trans = (const float*)d_in[1];
    const int* mask = (const int*)d_in[2];
    const int* tags = (const int*)d_in[3];
    float* out = (float*)d_out;

    (void)hipMemsetAsync(out, 0, sizeof(float), stream);
    crf_chain_kernel<<<dim3(kB * 8), dim3(64), 0, stream>>>(feats, trans, mask);
    crf_meet_kernel<<<dim3(kB), dim3(64), 0, stream>>>(feats, trans, mask, tags, out);
}